// Round 7
// baseline (299.971 us; speedup 1.0000x reference)
//
#include <hip/hip_runtime.h>
#include <math.h>

#define BB 32
#define PP 128
#define NN 1000
#define EMB 128
#define HH 8
#define FFH 128
#define PEN -100000.0f
#define CLIP 10.0f
#define EPS 1e-5f

// ---------------- reduction helpers (blockDim.x == 256) ----------------
__device__ inline float blockReduceMaxF(float v, volatile float* red) {
#pragma unroll
    for (int o = 32; o > 0; o >>= 1) v = fmaxf(v, __shfl_xor(v, o, 64));
    if ((threadIdx.x & 63) == 0) red[threadIdx.x >> 6] = v;
    __syncthreads();
    float r = fmaxf(fmaxf(red[0], red[1]), fmaxf(red[2], red[3]));
    __syncthreads();
    return r;
}

__device__ inline float blockReduceSumF(float v, volatile float* red) {
#pragma unroll
    for (int o = 32; o > 0; o >>= 1) v += __shfl_xor(v, o, 64);
    if ((threadIdx.x & 63) == 0) red[threadIdx.x >> 6] = v;
    __syncthreads();
    float r = red[0] + red[1] + red[2] + red[3];
    __syncthreads();
    return r;
}

// ================= K1: K/V projection, 512-thread register-tiled GEMM =================
__global__ __launch_bounds__(512) void gemm_kv(const float* __restrict__ enc,
                                               const float* __restrict__ Wk,
                                               const float* __restrict__ Wv,
                                               float* __restrict__ Kb,
                                               float* __restrict__ Vb) {
    int blk = blockIdx.x;
    int half = blk & 1;
    int chunk = (blk >> 1) & 7;
    int b = blk >> 4;
    const float* W = half ? Wv : Wk;
    float* Ob = half ? Vb : Kb;
    int n0 = chunk * 125;
    __shared__ float A_s[8][132];
    __shared__ float B_s[8][132];
    int tid = threadIdx.x;
    int tr = tid >> 5, tc = tid & 31;
    float acc[8][4];
#pragma unroll
    for (int i = 0; i < 8; i++)
#pragma unroll
        for (int j = 0; j < 4; j++) acc[i][j] = 0.f;

    for (int kk = 0; kk < 128; kk += 8) {
#pragma unroll
        for (int f = tid; f < 1024; f += 512) {
            int node = f >> 3, k = f & 7;
            A_s[k][node] = (node < 125)
                ? enc[((size_t)(b * 1000) + n0 + node) * 128 + kk + k] : 0.f;
        }
#pragma unroll
        for (int f = tid; f < 1024; f += 512) {
            int k = f >> 7, c = f & 127;
            B_s[k][c] = W[(kk + k) * 128 + c];
        }
        __syncthreads();
#pragma unroll
        for (int k = 0; k < 8; ++k) {
            float av[8], bv[4];
            *(float4*)&av[0] = *(const float4*)&A_s[k][tr * 8];
            *(float4*)&av[4] = *(const float4*)&A_s[k][tr * 8 + 4];
            *(float4*)&bv[0] = *(const float4*)&B_s[k][tc * 4];
#pragma unroll
            for (int i = 0; i < 8; ++i)
#pragma unroll
                for (int j = 0; j < 4; ++j) acc[i][j] = fmaf(av[i], bv[j], acc[i][j]);
        }
        __syncthreads();
    }
#pragma unroll
    for (int i = 0; i < 8; ++i) {
        int node = tr * 8 + i;
        if (node < 125) {
            float4 o = {acc[i][0], acc[i][1], acc[i][2], acc[i][3]};
            *(float4*)(Ob + ((size_t)(b * 1000) + n0 + node) * 128 + tc * 4) = o;
        }
    }
}

// ---------- K2: Q projection, 8-row stream style (grid 512, 1024 thr) ----------
__global__ __launch_bounds__(1024) void q_proj2(const float* __restrict__ eln,
                                                const float* __restrict__ load,
                                                const float* __restrict__ Wq,
                                                float* __restrict__ Q) {
    int r0 = blockIdx.x * 8;
    int tid = threadIdx.x;
    __shared__ float x_s[8 * 132];
    {
        int r = tid >> 7, c = tid & 127;
        x_s[r * 132 + c] = eln[(size_t)(r0 + r) * 128 + c];
    }
    __syncthreads();
    int r = tid >> 7, c = tid & 127;
    float acc = 0.f;
#pragma unroll 4
    for (int k = 0; k < 128; ++k) acc = fmaf(x_s[r * 132 + k], Wq[k * 128 + c], acc);
    acc = fmaf(load[r0 + r], Wq[16384 + c], acc);
    Q[(size_t)(r0 + r) * 128 + c] = acc * 0.25f;
}

// ---------------- mask transpose: [32][128][1000] -> [32][1000][128] ----------------
__global__ __launch_bounds__(256) void transpose_mask(const float* __restrict__ mask,
                                                      float* __restrict__ maskT) {
    __shared__ float t[32][33];
    int blk = blockIdx.x;
    int b = blk >> 7;
    int pt = (blk >> 5) & 3;
    int nt = blk & 31;
    int tx = threadIdx.x & 31, ty = threadIdx.x >> 5;
    int p0 = pt * 32, n0 = nt * 32;
#pragma unroll
    for (int r = 0; r < 32; r += 8) {
        int pp = p0 + ty + r, nn = n0 + tx;
        t[ty + r][tx] = (nn < 1000) ? mask[((size_t)b * 128 + pp) * 1000 + nn] : 0.f;
    }
    __syncthreads();
#pragma unroll
    for (int r = 0; r < 32; r += 8) {
        int nn = n0 + ty + r, pp = p0 + tx;
        if (nn < 1000) maskT[((size_t)b * 1000 + nn) * 128 + pp] = t[tx][ty + r];
    }
}

// ================= K3: attention, K in LDS, V global-broadcast, XCD swizzle =================
__global__ __launch_bounds__(512) void attention6(const float* __restrict__ Q,
                                                  const float* __restrict__ Kb,
                                                  const float* __restrict__ Vb,
                                                  const float* __restrict__ maskT,
                                                  float* __restrict__ OC) {
    int blk = blockIdx.x;
    int b = blk & 31, h = blk >> 5;
    int tid = threadIdx.x;
    __shared__ float lds[16000];
    float4* K4 = (float4*)lds;
    const size_t baseKV = (size_t)b * 128000 + h * 16;
    for (int f = tid; f < 4000; f += 512) {
        int n = f >> 2, d4 = f & 3;
        K4[f] = *(const float4*)(Kb + baseKV + (size_t)n * 128 + d4 * 4);
    }
    const float* Vbase = Vb + baseKV;
    int pg = tid & 31, ng = tid >> 5;
    int p0 = pg * 4;
    float4 qr[4][4];
#pragma unroll
    for (int j = 0; j < 4; ++j) {
        const float* qp = Q + ((size_t)(b * 128 + p0 + j)) * 128 + h * 16;
#pragma unroll
        for (int d4 = 0; d4 < 4; ++d4) qr[j][d4] = *(const float4*)(qp + d4 * 4);
    }
    const float* mT = maskT + (size_t)b * 128000 + p0;
    __syncthreads();

    float4 z = {0.f, 0.f, 0.f, 0.f};
    float4 Oa[4][4];
    float l4[4] = {0.f, 0.f, 0.f, 0.f};
#pragma unroll
    for (int j = 0; j < 4; ++j)
#pragma unroll
        for (int d4 = 0; d4 < 4; ++d4) Oa[j][d4] = z;

    int nlim = (ng < 8) ? 63 : 62;
#pragma unroll 1
    for (int i = 0; i < nlim; ++i) {
        int n = i * 16 + ng;
        int n4 = n * 4;
        float4 k0 = K4[n4], k1 = K4[n4 + 1], k2 = K4[n4 + 2], k3 = K4[n4 + 3];
        float4 v0 = *(const float4*)(Vbase + (size_t)n * 128);
        float4 v1 = *(const float4*)(Vbase + (size_t)n * 128 + 4);
        float4 v2 = *(const float4*)(Vbase + (size_t)n * 128 + 8);
        float4 v3 = *(const float4*)(Vbase + (size_t)n * 128 + 12);
        float4 mv = *(const float4*)(mT + (size_t)n * 128);
        float mva[4] = {mv.x, mv.y, mv.z, mv.w};
#pragma unroll
        for (int j = 0; j < 4; ++j) {
            float sA = qr[j][0].x * k0.x;
            sA = fmaf(qr[j][0].y, k0.y, sA);
            sA = fmaf(qr[j][0].z, k0.z, sA);
            sA = fmaf(qr[j][0].w, k0.w, sA);
            sA = fmaf(qr[j][1].x, k1.x, sA);
            sA = fmaf(qr[j][1].y, k1.y, sA);
            sA = fmaf(qr[j][1].z, k1.z, sA);
            sA = fmaf(qr[j][1].w, k1.w, sA);
            float sB = fmaf(qr[j][2].x, k2.x, mva[j]);
            sB = fmaf(qr[j][2].y, k2.y, sB);
            sB = fmaf(qr[j][2].z, k2.z, sB);
            sB = fmaf(qr[j][2].w, k2.w, sB);
            sB = fmaf(qr[j][3].x, k3.x, sB);
            sB = fmaf(qr[j][3].y, k3.y, sB);
            sB = fmaf(qr[j][3].z, k3.z, sB);
            sB = fmaf(qr[j][3].w, k3.w, sB);
            float e = __expf(sA + sB);
            l4[j] += e;
            Oa[j][0].x = fmaf(e, v0.x, Oa[j][0].x);
            Oa[j][0].y = fmaf(e, v0.y, Oa[j][0].y);
            Oa[j][0].z = fmaf(e, v0.z, Oa[j][0].z);
            Oa[j][0].w = fmaf(e, v0.w, Oa[j][0].w);
            Oa[j][1].x = fmaf(e, v1.x, Oa[j][1].x);
            Oa[j][1].y = fmaf(e, v1.y, Oa[j][1].y);
            Oa[j][1].z = fmaf(e, v1.z, Oa[j][1].z);
            Oa[j][1].w = fmaf(e, v1.w, Oa[j][1].w);
            Oa[j][2].x = fmaf(e, v2.x, Oa[j][2].x);
            Oa[j][2].y = fmaf(e, v2.y, Oa[j][2].y);
            Oa[j][2].z = fmaf(e, v2.z, Oa[j][2].z);
            Oa[j][2].w = fmaf(e, v2.w, Oa[j][2].w);
            Oa[j][3].x = fmaf(e, v3.x, Oa[j][3].x);
            Oa[j][3].y = fmaf(e, v3.y, Oa[j][3].y);
            Oa[j][3].z = fmaf(e, v3.z, Oa[j][3].z);
            Oa[j][3].w = fmaf(e, v3.w, Oa[j][3].w);
        }
    }
#pragma unroll
    for (int j = 0; j < 4; ++j) {
        l4[j] += __shfl_xor(l4[j], 32, 64);
#pragma unroll
        for (int d4 = 0; d4 < 4; ++d4) {
            Oa[j][d4].x += __shfl_xor(Oa[j][d4].x, 32, 64);
            Oa[j][d4].y += __shfl_xor(Oa[j][d4].y, 32, 64);
            Oa[j][d4].z += __shfl_xor(Oa[j][d4].z, 32, 64);
            Oa[j][d4].w += __shfl_xor(Oa[j][d4].w, 32, 64);
        }
    }
    __syncthreads();
    float* part = lds;
    int w = tid >> 6;
    bool lead = (tid & 32) == 0;
    if (w >= 4 && lead) {
        float* pb = part + (w - 4) * 2560;
#pragma unroll
        for (int j = 0; j < 4; ++j) {
            float* pr = pb + (p0 + j) * 20;
#pragma unroll
            for (int d4 = 0; d4 < 4; ++d4) *(float4*)(pr + d4 * 4) = Oa[j][d4];
            pr[16] = l4[j];
        }
    }
    __syncthreads();
    if (w < 4 && lead) {
        float* pb = part + w * 2560;
#pragma unroll
        for (int j = 0; j < 4; ++j) {
            float* pr = pb + (p0 + j) * 20;
#pragma unroll
            for (int d4 = 0; d4 < 4; ++d4) {
                float4 t = *(const float4*)(pr + d4 * 4);
                t.x += Oa[j][d4].x; t.y += Oa[j][d4].y;
                t.z += Oa[j][d4].z; t.w += Oa[j][d4].w;
                *(float4*)(pr + d4 * 4) = t;
            }
            pr[16] += l4[j];
        }
    }
    __syncthreads();
    {
        int p = tid >> 2, dg = tid & 3;
        float lsum = 0.f;
        float4 o = z;
#pragma unroll
        for (int w2 = 0; w2 < 4; ++w2) {
            const float* pr = part + w2 * 2560 + p * 20;
            lsum += pr[16];
            float4 t = *(const float4*)(pr + dg * 4);
            o.x += t.x; o.y += t.y; o.z += t.z; o.w += t.w;
        }
        float inv = 1.f / lsum;
        float4 r = {o.x * inv, o.y * inv, o.z * inv, o.w * inv};
        *(float4*)(OC + ((size_t)(b * 128 + p)) * 128 + h * 16 + dg * 4) = r;
    }
}

// ---------- K4: comb projection, 8-row stream style (grid 512, 1024 thr) ----------
__global__ __launch_bounds__(1024) void comb2(const float* __restrict__ OC,
                                              const float* __restrict__ Wc,
                                              const float* __restrict__ bc,
                                              float* __restrict__ MH) {
    int r0 = blockIdx.x * 8;
    int tid = threadIdx.x;
    __shared__ float x_s[8 * 132];
    {
        int r = tid >> 7, c = tid & 127;
        x_s[r * 132 + c] = OC[(size_t)(r0 + r) * 128 + c];
    }
    __syncthreads();
    int r = tid >> 7, c = tid & 127;
    float acc = bc[c];
#pragma unroll 4
    for (int k = 0; k < 128; ++k) acc = fmaf(x_s[r * 132 + k], Wc[k * 128 + c], acc);
    MH[(size_t)(r0 + r) * 128 + c] = acc;
}

// ================= K5: node scores, 512-thr register-tiled GEMM =================
__global__ __launch_bounds__(512) void gemm_score(const float* __restrict__ MH,
                                                  const float* __restrict__ enc,
                                                  float* __restrict__ SC) {
    int blk = blockIdx.x;
    int ph = blk & 1;
    int chunk = (blk >> 1) & 7;
    int b = blk >> 4;
    int n0 = chunk * 125;
    int p0 = ph * 64;
    __shared__ float A_s[8][68];
    __shared__ float B_s[8][132];
    int tid = threadIdx.x;
    int tr = tid >> 5, tc = tid & 31;
    float acc[4][4];
#pragma unroll
    for (int i = 0; i < 4; i++)
#pragma unroll
        for (int j = 0; j < 4; j++) acc[i][j] = 0.f;

    for (int kk = 0; kk < 128; kk += 8) {
        if (tid < 512) {
            int f = tid;
            int r = f >> 3, k = f & 7;
            A_s[k][r] = MH[((size_t)(b * 128) + p0 + r) * 128 + kk + k];
        }
#pragma unroll
        for (int f = tid; f < 1024; f += 512) {
            int nn = f >> 3, k = f & 7;
            B_s[k][nn] = (nn < 125)
                ? enc[((size_t)(b * 1000) + n0 + nn) * 128 + kk + k] : 0.f;
        }
        __syncthreads();
#pragma unroll
        for (int k = 0; k < 8; ++k) {
            float av[4], bv[4];
            *(float4*)&av[0] = *(const float4*)&A_s[k][tr * 4];
            *(float4*)&bv[0] = *(const float4*)&B_s[k][tc * 4];
#pragma unroll
            for (int i = 0; i < 4; ++i)
#pragma unroll
                for (int j = 0; j < 4; ++j) acc[i][j] = fmaf(av[i], bv[j], acc[i][j]);
        }
        __syncthreads();
    }
    const float invs = 0.08838834764831845f;
#pragma unroll
    for (int i = 0; i < 4; ++i) {
        int pp = p0 + tr * 4 + i;
#pragma unroll
        for (int j = 0; j < 4; ++j) {
            int n = tc * 4 + j;
            if (n < 125) SC[((size_t)(b * 128) + pp) * 1000 + n0 + n] = acc[i][j] * invs;
        }
    }
}

// ============ K6a: top-21 + xs-row construction (grid = 4096, 1 wave) ============
__global__ __launch_bounds__(64) void topk_xs(const float* __restrict__ dist,
                                              const float* __restrict__ theta,
                                              const float* __restrict__ f0,
                                              const float* __restrict__ f1,
                                              float* __restrict__ XS0, float* __restrict__ XS1,
                                              float* __restrict__ SD0, float* __restrict__ SD1,
                                              int* __restrict__ IDX) {
    int bp = blockIdx.x;
    int lane = threadIdx.x;
    __shared__ float selv[21];
    __shared__ int seli[21];
    __shared__ float sth[21];
    const float* drow = dist + (size_t)bp * 1000;
    unsigned long long key[16];
#pragma unroll
    for (int j = 0; j < 16; ++j) {
        int n = j * 64 + lane;
        key[j] = (n < 1000)
            ? ((((unsigned long long)__float_as_uint(drow[n])) << 32) | (unsigned)n)
            : ~0ull;
    }
    for (int t = 0; t < 21; ++t) {
        unsigned long long kmin = key[0];
        int jm = 0;
#pragma unroll
        for (int j = 1; j < 16; ++j)
            if (key[j] < kmin) { kmin = key[j]; jm = j; }
        unsigned long long g = kmin;
#pragma unroll
        for (int o = 1; o < 64; o <<= 1) {
            unsigned long long o2 = __shfl_xor(g, o, 64);
            g = (o2 < g) ? o2 : g;
        }
        if (kmin == g) key[jm] = ~0ull;
        if (lane == 0) {
            selv[t] = __uint_as_float((unsigned)(g >> 32));
            seli[t] = (int)(g & 0xffffffffu);
        }
    }
    __syncthreads();
    if (lane < 21) {
        int ix = seli[lane];
        sth[lane] = theta[(size_t)bp * 1000 + ix];
        IDX[(size_t)bp * 21 + lane] = ix;
    }
    __syncthreads();
    float m0 = selv[10], m1 = selv[20];
    if (lane < 11) {
        float sd = selv[lane] / m0;
        XS0[(size_t)bp * 24 + lane] = sd;
        XS0[(size_t)bp * 24 + 11 + lane] = sth[lane];
        SD0[(size_t)bp * 11 + lane] = sd;
    }
    if (lane < 21) {
        float sd = selv[lane] / m1;
        XS1[(size_t)bp * 44 + lane] = sd;
        XS1[(size_t)bp * 44 + 21 + lane] = sth[lane];
        SD1[(size_t)bp * 21 + lane] = sd;
    }
    if (lane == 0) {
        float a = f0[bp], c = f1[bp];
        XS0[(size_t)bp * 24 + 22] = a;
        XS0[(size_t)bp * 24 + 23] = c;
        XS1[(size_t)bp * 44 + 42] = a;
        XS1[(size_t)bp * 44 + 43] = c;
    }
}

// ============ K6b: policy front, register-tiled L1+L2 ============
// grid = 64 rowT x 2 colT x 2 pol = 256 blocks, 256 thr.
// Per block: 64 xs rows -> L1 e[64][128] (LDS-staged w1) -> L2 tile [64 x 128 cols].
__global__ __launch_bounds__(256) void policy_front3(
    const float* __restrict__ XS0, const float* __restrict__ XS1,
    const float* __restrict__ w1_0, const float* __restrict__ b1_0,
    const float* __restrict__ w2_0, const float* __restrict__ b2_0,
    const float* __restrict__ w1_1, const float* __restrict__ b1_1,
    const float* __restrict__ w2_1, const float* __restrict__ b2_1,
    float* __restrict__ Hb0, float* __restrict__ Hb1) {
    int blk = blockIdx.x;
    int pol = blk & 1, colT = (blk >> 1) & 1, rowT = blk >> 2;
    int r0 = rowT * 64, c0 = colT * 128;
    const float* XS = pol ? XS1 : XS0;
    const float* w1 = pol ? w1_1 : w1_0;
    const float* b1 = pol ? b1_1 : b1_0;
    const float* w2 = pol ? w2_1 : w2_0;
    const float* b2 = pol ? b2_1 : b2_0;
    float* Hb = pol ? Hb1 : Hb0;
    int XSW = pol ? 44 : 24;
    int tid = threadIdx.x;
    __shared__ float lds[16896];  // xs[2816] | w1/B_s[5632] | e[8448]
    float* xs_s = lds;
    float* w1_s = lds + 2816;   // 44*128 = 5632 max
    float* B_s = lds + 2816;    // aliases w1_s after L1 (8*132 = 1056)
    float* e_s = lds + 8448;    // [64][132]
    // stage xs rows + w1
    for (int f = tid; f < 64 * XSW; f += 256) {
        int r = f / XSW, k = f % XSW;
        xs_s[r * 44 + k] = XS[(size_t)(r0 + r) * XSW + k];
    }
    for (int f = tid; f < XSW * 128; f += 256) w1_s[f] = w1[f];
    __syncthreads();
    // L1: e = relu(xs @ w1 + b1), 8192 outputs, 32/thread
#pragma unroll
    for (int i = 0; i < 32; ++i) {
        int f = tid + i * 256;
        int r = f >> 7, c = f & 127;
        float acc = b1[c];
        for (int k = 0; k < XSW; ++k) acc = fmaf(xs_s[r * 44 + k], w1_s[k * 128 + c], acc);
        e_s[r * 132 + c] = fmaxf(acc, 0.f);
    }
    __syncthreads();
    // L2 tile: [64 rows x 128 cols], K=128 in chunks of 8; per thread 8x4
    int tr = tid >> 5, tc = tid & 31;  // tr 0..7 (8 rows), tc 0..31 (4 cols)
    float acc[8][4];
#pragma unroll
    for (int jj = 0; jj < 4; ++jj) {
        float bb = b2[c0 + tc * 4 + jj];
#pragma unroll
        for (int j = 0; j < 8; ++j) acc[j][jj] = bb;
    }
    for (int kk = 0; kk < 128; kk += 8) {
        __syncthreads();  // previous-iter B_s reads done
#pragma unroll
        for (int f = tid; f < 1024; f += 256) {
            int k = f >> 7, c = f & 127;
            B_s[k * 132 + c] = w2[(size_t)(kk + k) * 256 + c0 + c];
        }
        __syncthreads();
#pragma unroll
        for (int k = 0; k < 8; ++k) {
            float bv[4];
            *(float4*)&bv[0] = *(const float4*)&B_s[k * 132 + tc * 4];
#pragma unroll
            for (int j = 0; j < 8; ++j) {
                float av = e_s[(tr * 8 + j) * 132 + kk + k];
#pragma unroll
                for (int jj = 0; jj < 4; ++jj) acc[j][jj] = fmaf(av, bv[jj], acc[j][jj]);
            }
        }
    }
#pragma unroll
    for (int j = 0; j < 8; ++j) {
        float4 o = {fmaxf(acc[j][0], 0.f), fmaxf(acc[j][1], 0.f),
                    fmaxf(acc[j][2], 0.f), fmaxf(acc[j][3], 0.f)};
        *(float4*)(Hb + (size_t)(r0 + tr * 8 + j) * 256 + c0 + tc * 4) = o;
    }
}

// ---------------- K7: InstanceNorm stats, both policies (grid = 2B) ----------------
__global__ void inorm_both(const float* __restrict__ Hb0, const float* __restrict__ Hb1,
                           float* __restrict__ MUb, float* __restrict__ RSb) {
    int b = blockIdx.x >> 1;
    int pol = blockIdx.x & 1;
    const float* Hb = pol ? Hb1 : Hb0;
    int c = threadIdx.x;
    float s = 0.f, s2 = 0.f;
    for (int p = 0; p < 128; p++) {
        float v = Hb[((size_t)(b * 128 + p)) * 256 + c];
        s += v;
        s2 += v * v;
    }
    float mu = s * (1.f / 128.f);
    float var = s2 * (1.f / 128.f) - mu * mu;
    MUb[pol * 8192 + b * 256 + c] = mu;
    RSb[pol * 8192 + b * 256 + c] = rsqrtf(var + EPS);
}

// ============ K8: policy back, register-tiled norm+L3+L4 ============
// grid = 128 rowT x 2 pol = 256 blocks, 256 thr. Tile: 32 rows x 128 cols, K=256.
__global__ __launch_bounds__(256) void policy_back3(
    const float* __restrict__ Hb0, const float* __restrict__ Hb1,
    const float* __restrict__ MUb, const float* __restrict__ RSb,
    const float* __restrict__ g0, const float* __restrict__ be0,
    const float* __restrict__ w3_0, const float* __restrict__ b3_0,
    const float* __restrict__ w4_0, const float* __restrict__ b4_0,
    const float* __restrict__ g1, const float* __restrict__ be1,
    const float* __restrict__ w3_1, const float* __restrict__ b3_1,
    const float* __restrict__ w4_1, const float* __restrict__ b4_1,
    const float* __restrict__ SD0, const float* __restrict__ SD1,
    float* __restrict__ OUT0, float* __restrict__ OUT1) {
    int blk = blockIdx.x;
    int pol = blk & 1, rowT = blk >> 1;
    int r0 = rowT * 32, b = r0 >> 7;
    const float* Hb = pol ? Hb1 : Hb0;
    const float* MU = MUb + pol * 8192 + b * 256;
    const float* RS = RSb + pol * 8192 + b * 256;
    const float* gg = pol ? g1 : g0;
    const float* bb = pol ? be1 : be0;
    const float* w3 = pol ? w3_1 : w3_0;
    const float* b3 = pol ? b3_1 : b3_0;
    const float* w4 = pol ? w4_1 : w4_0;
    const float* b4 = pol ? b4_1 : b4_0;
    const float* SD = pol ? SD1 : SD0;
    float* OUT = pol ? OUT1 : OUT0;
    int ls = pol ? 21 : 11;
    int tid = threadIdx.x;
    __shared__ float scale_s[256], shift_s[256];
    __shared__ float A_s[16 * 36];    // [k][row], 32 rows + pad
    __shared__ float B_s[16 * 132];   // [k][c]
    __shared__ float e2_s[32 * 132];  // L3 output
    {
        float sc = RS[tid] * gg[tid];
        scale_s[tid] = sc;
        shift_s[tid] = bb[tid] - MU[tid] * sc;
    }
    __syncthreads();
    int tr = tid >> 5, tc = tid & 31;  // tr 0..7 (4 rows), tc 0..31 (4 cols)
    float acc[4][4];
#pragma unroll
    for (int jj = 0; jj < 4; ++jj) {
        float bv = b3[tc * 4 + jj];
#pragma unroll
        for (int j = 0; j < 4; ++j) acc[j][jj] = bv;
    }
    for (int kk = 0; kk < 256; kk += 16) {
        if (kk) __syncthreads();
        // stage A (norm applied): 32 rows x 16 k
#pragma unroll
        for (int f = tid; f < 512; f += 256) {
            int r = f >> 4, k = f & 15;
            float v = Hb[(size_t)(r0 + r) * 256 + kk + k];
            A_s[k * 36 + r] = v * scale_s[kk + k] + shift_s[kk + k];
        }
        // stage B: w3 16 k x 128 c
#pragma unroll
        for (int f = tid; f < 2048; f += 256) {
            int k = f >> 7, c = f & 127;
            B_s[k * 132 + c] = w3[(size_t)(kk + k) * 128 + c];
        }
        __syncthreads();
#pragma unroll
        for (int k = 0; k < 16; ++k) {
            float av[4], bv[4];
            *(float4*)&av[0] = *(const float4*)&A_s[k * 36 + tr * 4];
            *(float4*)&bv[0] = *(const float4*)&B_s[k * 132 + tc * 4];
#pragma unroll
            for (int j = 0; j < 4; ++j)
#pragma unroll
                for (int jj = 0; jj < 4; ++jj) acc[j][jj] = fmaf(av[j], bv[jj], acc[j][jj]);
        }
    }
    __syncthreads();
#pragma unroll
    for (int j = 0; j < 4; ++j) {
        float4 o = {fmaxf(acc[j][0], 0.f), fmaxf(acc[j][1], 0.f),
                    fmaxf(acc[j][2], 0.f), fmaxf(acc[j][3], 0.f)};
        *(float4*)&e2_s[(tr * 4 + j) * 132 + tc * 4] = o;
    }
    __syncthreads();
    // L4 + sd subtract: 32 x ls outputs
    for (int o = tid; o < 32 * ls; o += 256) {
        int row = o / ls, c = o % ls;
        float a = b4[c];
#pragma unroll 4
        for (int k = 0; k < 128; ++k) a = fmaf(e2_s[row * 132 + k], w4[k * ls + c], a);
        OUT[(size_t)(r0 + row) * ls + c] = a - SD[(size_t)(r0 + row) * ls + c];
    }
}

// ---------------- K9: combine + fast tanh clip + softmax ----------------
__global__ void final_softmax(const float* SC, const float* __restrict__ mask,
                              const int* __restrict__ IDX, const float* __restrict__ OUT0,
                              const float* __restrict__ OUT1, float* out) {
    int bp = blockIdx.x;
    int tid = threadIdx.x;
    __shared__ float a0[1000];
    __shared__ float a1[1000];
    __shared__ float red[4];
    for (int n = tid; n < 1000; n += 256) {
        a0[n] = PEN;
        a1[n] = PEN;
    }
    __syncthreads();
    if (tid < 11) a0[IDX[bp * 21 + tid]] = OUT0[bp * 11 + tid];
    if (tid < 21) a1[IDX[bp * 21 + tid]] = OUT1[bp * 21 + tid];
    __syncthreads();
    float logit[4];
    float lmax = -INFINITY;
    {
        int i = 0;
        for (int n = tid; n < 1000; n += 256, i++) {
            float sc = SC[(size_t)bp * 1000 + n] + 0.5f * (a0[n] + a1[n]);
            float zz = __expf(2.f * sc);
            float t = 1.f - 2.f / (zz + 1.f);
            float lg = CLIP * t + mask[(size_t)bp * 1000 + n];
            logit[i] = lg;
            lmax = fmaxf(lmax, lg);
        }
    }
    float m = blockReduceMaxF(lmax, red);
    float lsum = 0.f;
    {
        int i = 0;
        for (int n = tid; n < 1000; n += 256, i++) {
            float e = __expf(logit[i] - m);
            logit[i] = e;
            lsum += e;
        }
    }
    float s = blockReduceSumF(lsum, red);
    float inv = 1.f / s;
    {
        int i = 0;
        for (int n = tid; n < 1000; n += 256, i++) out[(size_t)bp * 1000 + n] = logit[i] * inv;
    }
}

// ---------------- launcher ----------------
extern "C" void kernel_launch(void* const* d_in, const int* in_sizes, int n_in,
                              void* d_out, int out_size, void* d_ws, size_t ws_size,
                              hipStream_t stream) {
    const float* eln   = (const float*)d_in[0];
    const float* load  = (const float*)d_in[1];
    const float* dist  = (const float*)d_in[2];
    const float* theta = (const float*)d_in[3];
    const float* f0    = (const float*)d_in[4];
    const float* f1    = (const float*)d_in[5];
    const float* mask  = (const float*)d_in[6];
    const float* enc   = (const float*)d_in[7];
    const float* Wq    = (const float*)d_in[8];
    const float* Wk    = (const float*)d_in[9];
    const float* Wv    = (const float*)d_in[10];
    const float* Wc    = (const float*)d_in[11];
    const float* bc    = (const float*)d_in[12];
    const float* p0w1 = (const float*)d_in[13];
    const float* p0b1 = (const float*)d_in[14];
    const float* p0w2 = (const float*)d_in[15];
    const float* p0b2 = (const float*)d_in[16];
    const float* p0w3 = (const float*)d_in[17];
    const float* p0b3 = (const float*)d_in[18];
    const float* p0w4 = (const float*)d_in[19];
    const float* p0b4 = (const float*)d_in[20];
    const float* p0g  = (const float*)d_in[21];
    const float* p0be = (const float*)d_in[22];
    const float* p1w1 = (const float*)d_in[23];
    const float* p1b1 = (const float*)d_in[24];
    const float* p1w2 = (const float*)d_in[25];
    const float* p1b2 = (const float*)d_in[26];
    const float* p1w3 = (const float*)d_in[27];
    const float* p1b3 = (const float*)d_in[28];
    const float* p1w4 = (const float*)d_in[29];
    const float* p1b4 = (const float*)d_in[30];
    const float* p1g  = (const float*)d_in[31];
    const float* p1be = (const float*)d_in[32];

    float* out = (float*)d_out;

    float* ws = (float*)d_ws;
    float* Kb   = ws;                     // 4,096,000
    float* Vb   = Kb + 4096000;           // 4,096,000
    float* Qb   = Vb + 4096000;           // 524,288
    float* OCb  = Qb + 524288;            // 524,288
    float* MHb  = OCb + 524288;           // 524,288  (aliases XS0/XS1 after gemm_score)
    float* Hb0  = MHb + 524288;           // 1,048,576
    float* Hb1  = Hb0 + 1048576;          // 1,048,576
    float* MUb  = Hb1 + 1048576;          // 16,384
    float* RSb  = MUb + 16384;            // 16,384
    float* SD0  = RSb + 16384;            // 45,056
    float* SD1  = SD0 + 45056;            // 86,016
    float* OUT0 = SD1 + 86016;            // 45,056
    float* OUT1 = OUT0 + 45056;           // 86,016
    int*   IDX  = (int*)(OUT1 + 86016);   // 86,016 ints

    // aliases (stream-ordered)
    float* XS0 = MHb;                     // written after gemm_score consumes MHb
    float* XS1 = MHb + 98304;
    float* maskT = out;                   // d_out as maskT until gemm_score overwrites with SC
    float* SC = out;

    gemm_kv<<<512, 512, 0, stream>>>(enc, Wk, Wv, Kb, Vb);
    q_proj2<<<512, 1024, 0, stream>>>(eln, load, Wq, Qb);
    transpose_mask<<<4096, 256, 0, stream>>>(mask, maskT);
    attention6<<<BB * HH, 512, 0, stream>>>(Qb, Kb, Vb, maskT, OCb);
    comb2<<<512, 1024, 0, stream>>>(OCb, Wc, bc, MHb);
    gemm_score<<<512, 512, 0, stream>>>(MHb, enc, SC);

    topk_xs<<<BB * PP, 64, 0, stream>>>(dist, theta, f0, f1, XS0, XS1, SD0, SD1, IDX);
    policy_front3<<<256, 256, 0, stream>>>(XS0, XS1,
                                           p0w1, p0b1, p0w2, p0b2,
                                           p1w1, p1b1, p1w2, p1b2,
                                           Hb0, Hb1);
    inorm_both<<<2 * BB, 256, 0, stream>>>(Hb0, Hb1, MUb, RSb);
    policy_back3<<<256, 256, 0, stream>>>(Hb0, Hb1, MUb, RSb,
                                          p0g, p0be, p0w3, p0b3, p0w4, p0b4,
                                          p1g, p1be, p1w3, p1b3, p1w4, p1b4,
                                          SD0, SD1, OUT0, OUT1);

    final_softmax<<<BB * PP, 256, 0, stream>>>(SC, mask, IDX, OUT0, OUT1, out);
}

// Round 8
// 264.009 us; speedup vs baseline: 1.1362x; 1.1362x over previous
//
#include <hip/hip_runtime.h>
#include <math.h>

#define BB 32
#define PP 128
#define NN 1000
#define EMB 128
#define HH 8
#define FFH 128
#define PEN -100000.0f
#define CLIP 10.0f
#define EPS 1e-5f

// ================== MEGA 1: gemm_kv | q_proj | transpose_mask | topk ==================
// grid = 3584 x 512 thr. [0,512) kv, [512,1024) qproj, [1024,3072) transpose, [3072,3584) topk
__global__ __launch_bounds__(512) void mega1(
    const float* __restrict__ enc, const float* __restrict__ Wk, const float* __restrict__ Wv,
    float* __restrict__ Kb, float* __restrict__ Vb,
    const float* __restrict__ eln, const float* __restrict__ load,
    const float* __restrict__ Wq, float* __restrict__ Q,
    const float* __restrict__ mask, float* __restrict__ maskT,
    const float* __restrict__ dist, const float* __restrict__ theta,
    const float* __restrict__ f0, const float* __restrict__ f1,
    float* __restrict__ XS0, float* __restrict__ XS1,
    float* __restrict__ SD0, float* __restrict__ SD1, int* __restrict__ IDX) {
    __shared__ float smem[2112];
    int blk = blockIdx.x;
    int tid = threadIdx.x;
    if (blk < 512) {
        // ---- K/V projection: per block 125 nodes x 128 cols, 8x4 micro-tile ----
        int half = blk & 1, chunk = (blk >> 1) & 7, b = blk >> 4;
        const float* W = half ? Wv : Wk;
        float* Ob = half ? Vb : Kb;
        int n0 = chunk * 125;
        float* A_s = smem;          // [8][132]
        float* B_s = smem + 1056;   // [8][132]
        int tr = tid >> 5, tc = tid & 31;
        float acc[8][4];
#pragma unroll
        for (int i = 0; i < 8; i++)
#pragma unroll
            for (int j = 0; j < 4; j++) acc[i][j] = 0.f;
        for (int kk = 0; kk < 128; kk += 8) {
#pragma unroll
            for (int f = tid; f < 1024; f += 512) {
                int node = f >> 3, k = f & 7;
                A_s[k * 132 + node] = (node < 125)
                    ? enc[((size_t)(b * 1000) + n0 + node) * 128 + kk + k] : 0.f;
            }
#pragma unroll
            for (int f = tid; f < 1024; f += 512) {
                int k = f >> 7, c = f & 127;
                B_s[k * 132 + c] = W[(kk + k) * 128 + c];
            }
            __syncthreads();
#pragma unroll
            for (int k = 0; k < 8; ++k) {
                float av[8], bv[4];
                *(float4*)&av[0] = *(const float4*)&A_s[k * 132 + tr * 8];
                *(float4*)&av[4] = *(const float4*)&A_s[k * 132 + tr * 8 + 4];
                *(float4*)&bv[0] = *(const float4*)&B_s[k * 132 + tc * 4];
#pragma unroll
                for (int i = 0; i < 8; ++i)
#pragma unroll
                    for (int j = 0; j < 4; ++j) acc[i][j] = fmaf(av[i], bv[j], acc[i][j]);
            }
            __syncthreads();
        }
#pragma unroll
        for (int i = 0; i < 8; ++i) {
            int node = tr * 8 + i;
            if (node < 125) {
                float4 o = {acc[i][0], acc[i][1], acc[i][2], acc[i][3]};
                *(float4*)(Ob + ((size_t)(b * 1000) + n0 + node) * 128 + tc * 4) = o;
            }
        }
    } else if (blk < 1024) {
        // ---- Q projection: 8 rows/block, 2 outputs/thread ----
        int r0 = (blk - 512) * 8;
        float* x_s = smem;  // [8][129]
#pragma unroll
        for (int f = tid; f < 1024; f += 512) {
            int r = f >> 7, c = f & 127;
            x_s[r * 129 + c] = eln[(size_t)(r0 + r) * 128 + c];
        }
        if (tid < 8) x_s[tid * 129 + 128] = load[r0 + tid];
        __syncthreads();
        int rr = tid >> 7, c = tid & 127;
        float a0 = 0.f, a1 = 0.f;
#pragma unroll 4
        for (int k = 0; k < 128; ++k) {
            float wv = Wq[k * 128 + c];
            a0 = fmaf(x_s[rr * 129 + k], wv, a0);
            a1 = fmaf(x_s[(rr + 4) * 129 + k], wv, a1);
        }
        {
            float wv = Wq[16384 + c];
            a0 = fmaf(x_s[rr * 129 + 128], wv, a0);
            a1 = fmaf(x_s[(rr + 4) * 129 + 128], wv, a1);
        }
        Q[(size_t)(r0 + rr) * 128 + c] = a0 * 0.25f;
        Q[(size_t)(r0 + rr + 4) * 128 + c] = a1 * 0.25f;
    } else if (blk < 3072) {
        // ---- mask transpose: two 32x32 tiles per block ----
        int t2 = (blk - 1024) * 2 + (tid >> 8);
        int tl = tid & 255;
        int b = t2 >> 7, pt = (t2 >> 5) & 3, nt = t2 & 31;
        int tx = tl & 31, ty = tl >> 5;
        float* t = smem + (tid >> 8) * 1056;  // [32][33]
        int p0 = pt * 32, n0 = nt * 32;
#pragma unroll
        for (int r = 0; r < 32; r += 8) {
            int pp = p0 + ty + r, nn = n0 + tx;
            t[(ty + r) * 33 + tx] = (nn < 1000) ? mask[((size_t)b * 128 + pp) * 1000 + nn] : 0.f;
        }
        __syncthreads();
#pragma unroll
        for (int r = 0; r < 32; r += 8) {
            int nn = n0 + ty + r, pp = p0 + tx;
            if (nn < 1000) maskT[((size_t)b * 1000 + nn) * 128 + pp] = t[tx * 33 + ty + r];
        }
    } else {
        // ---- top-21 + xs rows: 8 bp per block, one wave each, register-only ----
        int w = tid >> 6, lane = tid & 63;
        int bp = (blk - 3072) * 8 + w;
        const float* drow = dist + (size_t)bp * 1000;
        unsigned long long key[16];
#pragma unroll
        for (int j = 0; j < 16; ++j) {
            int n = j * 64 + lane;
            key[j] = (n < 1000)
                ? ((((unsigned long long)__float_as_uint(drow[n])) << 32) | (unsigned)n)
                : ~0ull;
        }
        float myv = 0.f, v10 = 0.f, v20 = 0.f;
        int myi = 0;
        for (int t = 0; t < 21; ++t) {
            unsigned long long kmin = key[0];
            int jm = 0;
#pragma unroll
            for (int j = 1; j < 16; ++j)
                if (key[j] < kmin) { kmin = key[j]; jm = j; }
            unsigned long long g = kmin;
#pragma unroll
            for (int o = 1; o < 64; o <<= 1) {
                unsigned long long o2 = __shfl_xor(g, o, 64);
                g = (o2 < g) ? o2 : g;
            }
            if (kmin == g) key[jm] = ~0ull;  // keys unique -> exactly one lane pops
            float gv = __uint_as_float((unsigned)(g >> 32));
            if (t == lane) { myv = gv; myi = (int)(g & 0xffffffffu); }
            if (t == 10) v10 = gv;
            if (t == 20) v20 = gv;
        }
        if (lane < 21) {
            float th = theta[(size_t)bp * 1000 + myi];
            IDX[(size_t)bp * 21 + lane] = myi;
            float sd1 = myv / v20;
            XS1[(size_t)bp * 44 + lane] = sd1;
            XS1[(size_t)bp * 44 + 21 + lane] = th;
            SD1[(size_t)bp * 21 + lane] = sd1;
            if (lane < 11) {
                float sd0 = myv / v10;
                XS0[(size_t)bp * 24 + lane] = sd0;
                XS0[(size_t)bp * 24 + 11 + lane] = th;
                SD0[(size_t)bp * 11 + lane] = sd0;
            }
        }
        if (lane == 0) {
            float a = f0[bp], c = f1[bp];
            XS0[(size_t)bp * 24 + 22] = a;
            XS0[(size_t)bp * 24 + 23] = c;
            XS1[(size_t)bp * 44 + 42] = a;
            XS1[(size_t)bp * 44 + 43] = c;
        }
    }
}

// ================== MEGA 2: attention | policy_front ==================
// grid = 512 x 512 thr. [0,256) attention (b=blk&31,h=blk>>5), [256,512) front
__global__ __launch_bounds__(512) void mega2(
    const float* __restrict__ Q, const float* __restrict__ Kb, const float* __restrict__ Vb,
    const float* __restrict__ maskT, float* __restrict__ OC,
    const float* __restrict__ XS0, const float* __restrict__ XS1,
    const float* __restrict__ w1_0, const float* __restrict__ b1_0,
    const float* __restrict__ w2_0, const float* __restrict__ b2_0,
    const float* __restrict__ w1_1, const float* __restrict__ b1_1,
    const float* __restrict__ w2_1, const float* __restrict__ b2_1,
    float* __restrict__ Hb0, float* __restrict__ Hb1) {
    __shared__ float smem[16000];
    int blk = blockIdx.x;
    int tid = threadIdx.x;
    if (blk < 256) {
        // ---------------- attention: K in LDS, V global, no-max softmax ----------------
        int b = blk & 31, h = blk >> 5;
        float4* K4 = (float4*)smem;
        const size_t baseKV = (size_t)b * 128000 + h * 16;
        for (int f = tid; f < 4000; f += 512) {
            int n = f >> 2, d4 = f & 3;
            K4[f] = *(const float4*)(Kb + baseKV + (size_t)n * 128 + d4 * 4);
        }
        const float* Vbase = Vb + baseKV;
        int pg = tid & 31, ng = tid >> 5;
        int p0 = pg * 4;
        float4 qr[4][4];
#pragma unroll
        for (int j = 0; j < 4; ++j) {
            const float* qp = Q + ((size_t)(b * 128 + p0 + j)) * 128 + h * 16;
#pragma unroll
            for (int d4 = 0; d4 < 4; ++d4) qr[j][d4] = *(const float4*)(qp + d4 * 4);
        }
        const float* mT = maskT + (size_t)b * 128000 + p0;
        __syncthreads();

        float4 z = {0.f, 0.f, 0.f, 0.f};
        float4 Oa[4][4];
        float l4[4] = {0.f, 0.f, 0.f, 0.f};
#pragma unroll
        for (int j = 0; j < 4; ++j)
#pragma unroll
            for (int d4 = 0; d4 < 4; ++d4) Oa[j][d4] = z;

        int nlim = (ng < 8) ? 63 : 62;
#pragma unroll 1
        for (int i = 0; i < nlim; ++i) {
            int n = i * 16 + ng;
            int n4 = n * 4;
            float4 k0 = K4[n4], k1 = K4[n4 + 1], k2 = K4[n4 + 2], k3 = K4[n4 + 3];
            float4 v0 = *(const float4*)(Vbase + (size_t)n * 128);
            float4 v1 = *(const float4*)(Vbase + (size_t)n * 128 + 4);
            float4 v2 = *(const float4*)(Vbase + (size_t)n * 128 + 8);
            float4 v3 = *(const float4*)(Vbase + (size_t)n * 128 + 12);
            float4 mv = *(const float4*)(mT + (size_t)n * 128);
            float mva[4] = {mv.x, mv.y, mv.z, mv.w};
#pragma unroll
            for (int j = 0; j < 4; ++j) {
                float sA = qr[j][0].x * k0.x;
                sA = fmaf(qr[j][0].y, k0.y, sA);
                sA = fmaf(qr[j][0].z, k0.z, sA);
                sA = fmaf(qr[j][0].w, k0.w, sA);
                sA = fmaf(qr[j][1].x, k1.x, sA);
                sA = fmaf(qr[j][1].y, k1.y, sA);
                sA = fmaf(qr[j][1].z, k1.z, sA);
                sA = fmaf(qr[j][1].w, k1.w, sA);
                float sB = fmaf(qr[j][2].x, k2.x, mva[j]);
                sB = fmaf(qr[j][2].y, k2.y, sB);
                sB = fmaf(qr[j][2].z, k2.z, sB);
                sB = fmaf(qr[j][2].w, k2.w, sB);
                sB = fmaf(qr[j][3].x, k3.x, sB);
                sB = fmaf(qr[j][3].y, k3.y, sB);
                sB = fmaf(qr[j][3].z, k3.z, sB);
                sB = fmaf(qr[j][3].w, k3.w, sB);
                float e = __expf(sA + sB);
                l4[j] += e;
                Oa[j][0].x = fmaf(e, v0.x, Oa[j][0].x);
                Oa[j][0].y = fmaf(e, v0.y, Oa[j][0].y);
                Oa[j][0].z = fmaf(e, v0.z, Oa[j][0].z);
                Oa[j][0].w = fmaf(e, v0.w, Oa[j][0].w);
                Oa[j][1].x = fmaf(e, v1.x, Oa[j][1].x);
                Oa[j][1].y = fmaf(e, v1.y, Oa[j][1].y);
                Oa[j][1].z = fmaf(e, v1.z, Oa[j][1].z);
                Oa[j][1].w = fmaf(e, v1.w, Oa[j][1].w);
                Oa[j][2].x = fmaf(e, v2.x, Oa[j][2].x);
                Oa[j][2].y = fmaf(e, v2.y, Oa[j][2].y);
                Oa[j][2].z = fmaf(e, v2.z, Oa[j][2].z);
                Oa[j][2].w = fmaf(e, v2.w, Oa[j][2].w);
                Oa[j][3].x = fmaf(e, v3.x, Oa[j][3].x);
                Oa[j][3].y = fmaf(e, v3.y, Oa[j][3].y);
                Oa[j][3].z = fmaf(e, v3.z, Oa[j][3].z);
                Oa[j][3].w = fmaf(e, v3.w, Oa[j][3].w);
            }
        }
#pragma unroll
        for (int j = 0; j < 4; ++j) {
            l4[j] += __shfl_xor(l4[j], 32, 64);
#pragma unroll
            for (int d4 = 0; d4 < 4; ++d4) {
                Oa[j][d4].x += __shfl_xor(Oa[j][d4].x, 32, 64);
                Oa[j][d4].y += __shfl_xor(Oa[j][d4].y, 32, 64);
                Oa[j][d4].z += __shfl_xor(Oa[j][d4].z, 32, 64);
                Oa[j][d4].w += __shfl_xor(Oa[j][d4].w, 32, 64);
            }
        }
        __syncthreads();
        float* part = smem;  // [4][128][20]
        int w = tid >> 6;
        bool lead = (tid & 32) == 0;
        if (w >= 4 && lead) {
            float* pb = part + (w - 4) * 2560;
#pragma unroll
            for (int j = 0; j < 4; ++j) {
                float* pr = pb + (p0 + j) * 20;
#pragma unroll
                for (int d4 = 0; d4 < 4; ++d4) *(float4*)(pr + d4 * 4) = Oa[j][d4];
                pr[16] = l4[j];
            }
        }
        __syncthreads();
        if (w < 4 && lead) {
            float* pb = part + w * 2560;
#pragma unroll
            for (int j = 0; j < 4; ++j) {
                float* pr = pb + (p0 + j) * 20;
#pragma unroll
                for (int d4 = 0; d4 < 4; ++d4) {
                    float4 t = *(const float4*)(pr + d4 * 4);
                    t.x += Oa[j][d4].x; t.y += Oa[j][d4].y;
                    t.z += Oa[j][d4].z; t.w += Oa[j][d4].w;
                    *(float4*)(pr + d4 * 4) = t;
                }
                pr[16] += l4[j];
            }
        }
        __syncthreads();
        {
            int p = tid >> 2, dg = tid & 3;
            float lsum = 0.f;
            float4 o = z;
#pragma unroll
            for (int w2 = 0; w2 < 4; ++w2) {
                const float* pr = part + w2 * 2560 + p * 20;
                lsum += pr[16];
                float4 t = *(const float4*)(pr + dg * 4);
                o.x += t.x; o.y += t.y; o.z += t.z; o.w += t.w;
            }
            float inv = 1.f / lsum;
            float4 r = {o.x * inv, o.y * inv, o.z * inv, o.w * inv};
            *(float4*)(OC + ((size_t)(b * 128 + p)) * 128 + h * 16 + dg * 4) = r;
        }
    } else {
        // ---------------- policy front: 64 rows x 128 cols tile, L1+L2 fused ----------------
        int fb = blk - 256;
        int pol = fb & 1, colT = (fb >> 1) & 1, rowT = fb >> 2;
        int r0 = rowT * 64, c0 = colT * 128;
        const float* XS = pol ? XS1 : XS0;
        const float* w1 = pol ? w1_1 : w1_0;
        const float* b1 = pol ? b1_1 : b1_0;
        const float* w2 = pol ? w2_1 : w2_0;
        const float* b2 = pol ? b2_1 : b2_0;
        float* Hb = pol ? Hb1 : Hb0;
        int XSW = pol ? 44 : 24;
        float* xs_s = smem;          // [64][44]
        float* e_s = smem + 2816;    // [64][132]
        float* B_s = smem + 11264;   // [8][132]
        for (int f = tid; f < 64 * XSW; f += 512) {
            int r = f / XSW, k = f % XSW;
            xs_s[r * 44 + k] = XS[(size_t)(r0 + r) * XSW + k];
        }
        __syncthreads();
        // L1: 8192 outputs, 16/thread; w1 streamed from L2 (broadcast across rows)
#pragma unroll
        for (int i = 0; i < 16; ++i) {
            int f = tid + i * 512;
            int r = f >> 7, c = f & 127;
            float acc = b1[c];
            for (int k = 0; k < XSW; ++k) acc = fmaf(xs_s[r * 44 + k], w1[k * 128 + c], acc);
            e_s[r * 132 + c] = fmaxf(acc, 0.f);
        }
        __syncthreads();
        // L2: [64 x 128] tile, K=128 in 8-chunks, per thread 4x4
        int tr = tid >> 5, tc = tid & 31;
        float acc[4][4];
#pragma unroll
        for (int jj = 0; jj < 4; ++jj) {
            float bb = b2[c0 + tc * 4 + jj];
#pragma unroll
            for (int j = 0; j < 4; ++j) acc[j][jj] = bb;
        }
        for (int kk = 0; kk < 128; kk += 8) {
#pragma unroll
            for (int f = tid; f < 1024; f += 512) {
                int k = f >> 7, c = f & 127;
                B_s[k * 132 + c] = w2[(size_t)(kk + k) * 256 + c0 + c];
            }
            __syncthreads();
#pragma unroll
            for (int k = 0; k < 8; ++k) {
                float av[4], bv[4];
#pragma unroll
                for (int j = 0; j < 4; ++j) av[j] = e_s[(tr * 4 + j) * 132 + kk + k];
                *(float4*)&bv[0] = *(const float4*)&B_s[k * 132 + tc * 4];
#pragma unroll
                for (int j = 0; j < 4; ++j)
#pragma unroll
                    for (int jj = 0; jj < 4; ++jj) acc[j][jj] = fmaf(av[j], bv[jj], acc[j][jj]);
            }
            __syncthreads();
        }
#pragma unroll
        for (int j = 0; j < 4; ++j) {
            float4 o = {fmaxf(acc[j][0], 0.f), fmaxf(acc[j][1], 0.f),
                        fmaxf(acc[j][2], 0.f), fmaxf(acc[j][3], 0.f)};
            *(float4*)(Hb + (size_t)(r0 + tr * 4 + j) * 256 + c0 + tc * 4) = o;
        }
    }
}

// ================== MEGA 3: comb_proj | inorm ==================
// grid = 576 x 512 thr. [0,512) comb (8 rows each), [512,576) inorm
__global__ __launch_bounds__(512) void mega3(
    const float* __restrict__ OC, const float* __restrict__ Wc, const float* __restrict__ bc,
    float* __restrict__ MH,
    const float* __restrict__ Hb0, const float* __restrict__ Hb1,
    float* __restrict__ MUb, float* __restrict__ RSb) {
    __shared__ float smem[1056];
    int blk = blockIdx.x;
    int tid = threadIdx.x;
    if (blk < 512) {
        int r0 = blk * 8;
        float* x_s = smem;  // [8][129] (129 pad vs bank conflicts)
#pragma unroll
        for (int f = tid; f < 1024; f += 512) {
            int r = f >> 7, c = f & 127;
            x_s[r * 129 + c] = OC[(size_t)(r0 + r) * 128 + c];
        }
        __syncthreads();
        int rr = tid >> 7, c = tid & 127;
        float a0 = bc[c], a1 = a0;
#pragma unroll 4
        for (int k = 0; k < 128; ++k) {
            float wv = Wc[k * 128 + c];
            a0 = fmaf(x_s[rr * 129 + k], wv, a0);
            a1 = fmaf(x_s[(rr + 4) * 129 + k], wv, a1);
        }
        MH[(size_t)(r0 + rr) * 128 + c] = a0;
        MH[(size_t)(r0 + rr + 4) * 128 + c] = a1;
    } else {
        int ib = blk - 512;
        int pol = ib & 1, b = ib >> 1;
        const float* Hb = pol ? Hb1 : Hb0;
        int c = tid & 255, half = tid >> 8;
        float s = 0.f, s2 = 0.f;
        int pbase = half * 64;
        for (int p = pbase; p < pbase + 64; ++p) {
            float v = Hb[((size_t)(b * 128 + p)) * 256 + c];
            s += v;
            s2 += v * v;
        }
        float* s_s = smem;          // [512]
        float* s2_s = smem + 512;   // [512]
        s_s[half * 256 + c] = s;
        s2_s[half * 256 + c] = s2;
        __syncthreads();
        if (half == 0) {
            float S = s_s[c] + s_s[256 + c];
            float S2 = s2_s[c] + s2_s[256 + c];
            float mu = S * (1.f / 128.f);
            float var = S2 * (1.f / 128.f) - mu * mu;
            MUb[pol * 8192 + b * 256 + c] = mu;
            RSb[pol * 8192 + b * 256 + c] = rsqrtf(var + EPS);
        }
    }
}

// ================== MEGA 4: gemm_score | policy_back ==================
// grid = 640 x 512 thr. [0,512) score, [512,640) back (64 rows x 128 cols, K=256)
__global__ __launch_bounds__(512) void mega4(
    const float* __restrict__ MH, const float* __restrict__ enc, float* __restrict__ SC,
    const float* __restrict__ Hb0, const float* __restrict__ Hb1,
    const float* __restrict__ MUb, const float* __restrict__ RSb,
    const float* __restrict__ g0, const float* __restrict__ be0,
    const float* __restrict__ w3_0, const float* __restrict__ b3_0,
    const float* __restrict__ w4_0, const float* __restrict__ b4_0,
    const float* __restrict__ g1, const float* __restrict__ be1,
    const float* __restrict__ w3_1, const float* __restrict__ b3_1,
    const float* __restrict__ w4_1, const float* __restrict__ b4_1,
    const float* __restrict__ SD0, const float* __restrict__ SD1,
    float* __restrict__ OUT0, float* __restrict__ OUT1) {
    __shared__ float smem[12160];
    int blk = blockIdx.x;
    int tid = threadIdx.x;
    if (blk < 512) {
        // ---- node scores: 64 p x 125 n tile, 4x4/thread ----
        int ph = blk & 1, chunk = (blk >> 1) & 7, b = blk >> 4;
        int n0 = chunk * 125, p0 = ph * 64;
        float* A_s = smem;          // [8][68]
        float* B_s = smem + 544;    // [8][132]
        int tr = tid >> 5, tc = tid & 31;
        float acc[4][4];
#pragma unroll
        for (int i = 0; i < 4; i++)
#pragma unroll
            for (int j = 0; j < 4; j++) acc[i][j] = 0.f;
        for (int kk = 0; kk < 128; kk += 8) {
            {
                int r = tid >> 3, k = tid & 7;
                A_s[k * 68 + r] = MH[((size_t)(b * 128) + p0 + r) * 128 + kk + k];
            }
#pragma unroll
            for (int f = tid; f < 1024; f += 512) {
                int nn = f >> 3, k = f & 7;
                B_s[k * 132 + nn] = (nn < 125)
                    ? enc[((size_t)(b * 1000) + n0 + nn) * 128 + kk + k] : 0.f;
            }
            __syncthreads();
#pragma unroll
            for (int k = 0; k < 8; ++k) {
                float av[4], bv[4];
                *(float4*)&av[0] = *(const float4*)&A_s[k * 68 + tr * 4];
                *(float4*)&bv[0] = *(const float4*)&B_s[k * 132 + tc * 4];
#pragma unroll
                for (int i = 0; i < 4; ++i)
#pragma unroll
                    for (int j = 0; j < 4; ++j) acc[i][j] = fmaf(av[i], bv[j], acc[i][j]);
            }
            __syncthreads();
        }
        const float invs = 0.08838834764831845f;
#pragma unroll
        for (int i = 0; i < 4; ++i) {
            int pp = p0 + tr * 4 + i;
#pragma unroll
            for (int j = 0; j < 4; ++j) {
                int n = tc * 4 + j;
                if (n < 125) SC[((size_t)(b * 128) + pp) * 1000 + n0 + n] = acc[i][j] * invs;
            }
        }
    } else {
        // ---- policy back: 64 rows x 128 cols, norm fused into A-stage, L4 fused ----
        int bb2 = blk - 512;
        int pol = bb2 & 1, rowT = bb2 >> 1;
        int r0 = rowT * 64, b = r0 >> 7;
        const float* Hb = pol ? Hb1 : Hb0;
        const float* MU = MUb + pol * 8192 + b * 256;
        const float* RS = RSb + pol * 8192 + b * 256;
        const float* gg = pol ? g1 : g0;
        const float* bbv = pol ? be1 : be0;
        const float* w3 = pol ? w3_1 : w3_0;
        const float* pb3 = pol ? b3_1 : b3_0;
        const float* w4 = pol ? w4_1 : w4_0;
        const float* pb4 = pol ? b4_1 : b4_0;
        const float* SD = pol ? SD1 : SD0;
        float* OUT = pol ? OUT1 : OUT0;
        int ls = pol ? 21 : 11;
        float* scale_s = smem;            // [256]
        float* shift_s = smem + 256;      // [256]
        float* A_s = smem + 512;          // [16][68]
        float* B_s = smem + 1600;         // [16][132]
        float* e2_s = smem + 3712;        // [64][132]
        if (tid < 256) {
            float sc = RS[tid] * gg[tid];
            scale_s[tid] = sc;
            shift_s[tid] = bbv[tid] - MU[tid] * sc;
        }
        __syncthreads();
        int tr = tid >> 5, tc = tid & 31;
        float acc[4][4];
#pragma unroll
        for (int jj = 0; jj < 4; ++jj) {
            float bv = pb3[tc * 4 + jj];
#pragma unroll
            for (int j = 0; j < 4; ++j) acc[j][jj] = bv;
        }
        for (int kk = 0; kk < 256; kk += 16) {
            // stage A (64 rows x 16 k, normed)
#pragma unroll
            for (int f = tid; f < 1024; f += 512) {
                int r = f >> 4, k = f & 15;
                float v = Hb[(size_t)(r0 + r) * 256 + kk + k];
                A_s[k * 68 + r] = v * scale_s[kk + k] + shift_s[kk + k];
            }
            // stage B (w3: 16 k x 128 c)
#pragma unroll
            for (int f = tid; f < 2048; f += 512) {
                int k = f >> 7, c = f & 127;
                B_s[k * 132 + c] = w3[(size_t)(kk + k) * 128 + c];
            }
            __syncthreads();
#pragma unroll
            for (int k = 0; k < 16; ++k) {
                float av[4], bv[4];
                *(float4*)&av[0] = *(const float4*)&A_s[k * 68 + tr * 4];
                *(float4*)&bv[0] = *(const float4*)&B_s[k * 132 + tc * 4];
#pragma unroll
                for (int j = 0; j < 4; ++j)
#pragma unroll
                    for (int jj = 0; jj < 4; ++jj) acc[j][jj] = fmaf(av[j], bv[jj], acc[j][jj]);
            }
            __syncthreads();
        }
#pragma unroll
        for (int j = 0; j < 4; ++j) {
            float4 o = {fmaxf(acc[j][0], 0.f), fmaxf(acc[j][1], 0.f),
                        fmaxf(acc[j][2], 0.f), fmaxf(acc[j][3], 0.f)};
            *(float4*)&e2_s[(tr * 4 + j) * 132 + tc * 4] = o;
        }
        __syncthreads();
        // L4 + sd subtract: 64 x ls outputs
        for (int o = tid; o < 64 * ls; o += 512) {
            int row = o / ls, c = o % ls;
            float a = pb4[c];
#pragma unroll 4
            for (int k = 0; k < 128; ++k) a = fmaf(e2_s[row * 132 + k], w4[k * ls + c], a);
            OUT[(size_t)(r0 + row) * ls + c] = a - SD[(size_t)(r0 + row) * ls + c];
        }
    }
}

// ---------------- K9: combine + fast tanh clip + softmax (256 thr) ----------------
__device__ inline float blockReduceMaxF(float v, volatile float* red) {
#pragma unroll
    for (int o = 32; o > 0; o >>= 1) v = fmaxf(v, __shfl_xor(v, o, 64));
    if ((threadIdx.x & 63) == 0) red[threadIdx.x >> 6] = v;
    __syncthreads();
    float r = fmaxf(fmaxf(red[0], red[1]), fmaxf(red[2], red[3]));
    __syncthreads();
    return r;
}

__device__ inline float blockReduceSumF(float v, volatile float* red) {
#pragma unroll
    for (int o = 32; o > 0; o >>= 1) v += __shfl_xor(v, o, 64);
    if ((threadIdx.x & 63) == 0) red[threadIdx.x >> 6] = v;
    __syncthreads();
    float r = red[0] + red[1] + red[2] + red[3];
    __syncthreads();
    return r;
}

__global__ void final_softmax(const float* SC, const float* __restrict__ mask,
                              const int* __restrict__ IDX, const float* __restrict__ OUT0,
                              const float* __restrict__ OUT1, float* out) {
    int bp = blockIdx.x;
    int tid = threadIdx.x;
    __shared__ float a0[1000];
    __shared__ float a1[1000];
    __shared__ float red[4];
    for (int n = tid; n < 1000; n += 256) {
        a0[n] = PEN;
        a1[n] = PEN;
    }
    __syncthreads();
    if (tid < 11) a0[IDX[bp * 21 + tid]] = OUT0[bp * 11 + tid];
    if (tid < 21) a1[IDX[bp * 21 + tid]] = OUT1[bp * 21 + tid];
    __syncthreads();
    float logit[4];
    float lmax = -INFINITY;
    {
        int i = 0;
        for (int n = tid; n < 1000; n += 256, i++) {
            float sc = SC[(size_t)bp * 1000 + n] + 0.5f * (a0[n] + a1[n]);
            float zz = __expf(2.f * sc);
            float t = 1.f - 2.f / (zz + 1.f);
            float lg = CLIP * t + mask[(size_t)bp * 1000 + n];
            logit[i] = lg;
            lmax = fmaxf(lmax, lg);
        }
    }
    float m = blockReduceMaxF(lmax, red);
    float lsum = 0.f;
    {
        int i = 0;
        for (int n = tid; n < 1000; n += 256, i++) {
            float e = __expf(logit[i] - m);
            logit[i] = e;
            lsum += e;
        }
    }
    float s = blockReduceSumF(lsum, red);
    float inv = 1.f / s;
    {
        int i = 0;
        for (int n = tid; n < 1000; n += 256, i++) out[(size_t)bp * 1000 + n] = logit[i] * inv;
    }
}

// ---------------- launcher ----------------
extern "C" void kernel_launch(void* const* d_in, const int* in_sizes, int n_in,
                              void* d_out, int out_size, void* d_ws, size_t ws_size,
                              hipStream_t stream) {
    const float* eln   = (const float*)d_in[0];
    const float* load  = (const float*)d_in[1];
    const float* dist  = (const float*)d_in[2];
    const float* theta = (const float*)d_in[3];
    const float* f0    = (const float*)d_in[4];
    const float* f1    = (const float*)d_in[5];
    const float* mask  = (const float*)d_in[6];
    const float* enc   = (const float*)d_in[7];
    const float* Wq    = (const float*)d_in[8];
    const float* Wk    = (const float*)d_in[9];
    const float* Wv    = (const float*)d_in[10];
    const float* Wc    = (const float*)d_in[11];
    const float* bc    = (const float*)d_in[12];
    const float* p0w1 = (const float*)d_in[13];
    const float* p0b1 = (const float*)d_in[14];
    const float* p0w2 = (const float*)d_in[15];
    const float* p0b2 = (const float*)d_in[16];
    const float* p0w3 = (const float*)d_in[17];
    const float* p0b3 = (const float*)d_in[18];
    const float* p0w4 = (const float*)d_in[19];
    const float* p0b4 = (const float*)d_in[20];
    const float* p0g  = (const float*)d_in[21];
    const float* p0be = (const float*)d_in[22];
    const float* p1w1 = (const float*)d_in[23];
    const float* p1b1 = (const float*)d_in[24];
    const float* p1w2 = (const float*)d_in[25];
    const float* p1b2 = (const float*)d_in[26];
    const float* p1w3 = (const float*)d_in[27];
    const float* p1b3 = (const float*)d_in[28];
    const float* p1w4 = (const float*)d_in[29];
    const float* p1b4 = (const float*)d_in[30];
    const float* p1g  = (const float*)d_in[31];
    const float* p1be = (const float*)d_in[32];

    float* out = (float*)d_out;

    float* ws = (float*)d_ws;
    float* Kb   = ws;                     // 4,096,000
    float* Vb   = Kb + 4096000;           // 4,096,000
    float* Qb   = Vb + 4096000;           // 524,288
    float* OCb  = Qb + 524288;            // 524,288
    float* MHb  = OCb + 524288;           // 524,288
    float* Hb0  = MHb + 524288;           // 1,048,576
    float* Hb1  = Hb0 + 1048576;          // 1,048,576
    float* MUb  = Hb1 + 1048576;          // 16,384
    float* RSb  = MUb + 16384;            // 16,384
    float* SD0  = RSb + 16384;            // 45,056
    float* SD1  = SD0 + 45056;            // 86,016
    float* OUT0 = SD1 + 86016;            // 45,056
    float* OUT1 = OUT0 + 45056;           // 86,016
    int*   IDX  = (int*)(OUT1 + 86016);   // 86,016 ints
    float* XS0  = (float*)(IDX + 86016);  // 98,304
    float* XS1  = XS0 + 98304;            // 180,224

    // d_out as maskT (mega1->mega2), then gemm_score (mega4) overwrites with SC
    float* maskT = out;
    float* SC = out;

    mega1<<<3584, 512, 0, stream>>>(enc, Wk, Wv, Kb, Vb,
                                    eln, load, Wq, Qb,
                                    mask, maskT,
                                    dist, theta, f0, f1, XS0, XS1, SD0, SD1, IDX);
    mega2<<<512, 512, 0, stream>>>(Qb, Kb, Vb, maskT, OCb,
                                   XS0, XS1,
                                   p0w1, p0b1, p0w2, p0b2,
                                   p1w1, p1b1, p1w2, p1b2,
                                   Hb0, Hb1);
    mega3<<<576, 512, 0, stream>>>(OCb, Wc, bc, MHb, Hb0, Hb1, MUb, RSb);
    mega4<<<640, 512, 0, stream>>>(MHb, enc, SC,
                                   Hb0, Hb1, MUb, RSb,
                                   p0g, p0be, p0w3, p0b3, p0w4, p0b4,
                                   p1g, p1be, p1w3, p1b3, p1w4, p1b4,
                                   SD0, SD1, OUT0, OUT1);
    final_softmax<<<BB * PP, 256, 0, stream>>>(SC, mask, IDX, OUT0, OUT1, out);
}